// Round 1
// baseline (120.319 us; speedup 1.0000x reference)
//
#include <hip/hip_runtime.h>

#define B_ 8
#define N_ 512
#define F_ 128
#define H_ 4
#define U_ 32
#define LEAKY_ALPHA 0.2f

// ---------------------------------------------------------------------------
// Kernel 1: projections.
//   hsrc[b,h,n,u] = sum_f x[b,n,f] * Wsrc[h,f,u]   (same for hdst/Wdst)
//   Arow[b,h,n]   = sum_u a[h,u] * hsrc[b,h,n,u]
//   Drow[b,h,n]   = sum_u a[h,u] * hdst[b,h,n,u]
// Block = 16 consecutive flat rows (b*N+n), thread = one of 256 output
// columns (which 2 x h 4 x u 32). W element loaded once, reused 16x.
// ---------------------------------------------------------------------------
__global__ __launch_bounds__(256) void proj_kernel(
    const float* __restrict__ x, const float* __restrict__ Wsrc,
    const float* __restrict__ Wdst, const float* __restrict__ a,
    float* __restrict__ hsrc, float* __restrict__ hdst,
    float* __restrict__ Arow, float* __restrict__ Drow)
{
    __shared__ float4 xlds[16 * 32];          // 16 rows x 128 floats
    const int t  = threadIdx.x;
    const int r0 = blockIdx.x * 16;           // first flat row (b*N+n)

    const float4* xg = (const float4*)x + (size_t)r0 * 32;
    xlds[t]       = xg[t];
    xlds[t + 256] = xg[t + 256];
    __syncthreads();

    const int u     = t & 31;
    const int h     = (t >> 5) & 3;
    const int which = t >> 7;                 // 0 = src, 1 = dst
    const float* W  = (which ? Wdst : Wsrc) + h * (F_ * U_) + u;

    float acc[16];
#pragma unroll
    for (int r = 0; r < 16; ++r) acc[r] = 0.f;

    for (int fc = 0; fc < 32; ++fc) {
        const float w0 = W[(4 * fc + 0) * U_];
        const float w1 = W[(4 * fc + 1) * U_];
        const float w2 = W[(4 * fc + 2) * U_];
        const float w3 = W[(4 * fc + 3) * U_];
#pragma unroll
        for (int r = 0; r < 16; ++r) {
            const float4 xv = xlds[r * 32 + fc];
            float s = acc[r];
            s = fmaf(xv.x, w0, s);
            s = fmaf(xv.y, w1, s);
            s = fmaf(xv.z, w2, s);
            s = fmaf(xv.w, w3, s);
            acc[r] = s;
        }
    }

    const float av = a[h * U_ + u];
    float* outp = which ? hdst : hsrc;
    float* redp = which ? Drow : Arow;

#pragma unroll
    for (int r = 0; r < 16; ++r) {
        const int row = r0 + r;               // = b*N + n
        const int b = row >> 9, n = row & (N_ - 1);
        outp[((size_t)((b * H_ + h) * N_ + n) << 5) + u] = acc[r];
        // reduce a_u * acc over the 32 u-lanes (32-aligned groups in wave64)
        float v = acc[r] * av;
        v += __shfl_xor(v, 1);
        v += __shfl_xor(v, 2);
        v += __shfl_xor(v, 4);
        v += __shfl_xor(v, 8);
        v += __shfl_xor(v, 16);
        if (u == 0) redp[(b * H_ + h) * N_ + n] = v;
    }
}

// ---------------------------------------------------------------------------
// Kernel 2: attention. Block = (b, h, tile of 16 i-rows), 256 threads.
// Thread = (i = t>>4, sub = t&15). s_i and a live in VGPRs; h_dst (phase A)
// and h_src (phase C) staged in LDS 128-row tiles, rows padded to 36 floats
// (breaks the 128B-stride all-lanes-one-bank-group pathology).
// Scores stay in 32 registers across phase A -> softmax; only exp'd p goes
// to LDS (rows padded to 520 floats so the 4 i-groups hit distinct banks).
// ---------------------------------------------------------------------------
#define DT_STRIDE 36
#define PL_STRIDE 520

__global__ __launch_bounds__(256, 3) void attn_kernel(
    const float* __restrict__ hsrc, const float* __restrict__ hdst,
    const float* __restrict__ Arow, const float* __restrict__ Drow,
    const float* __restrict__ a, float* __restrict__ out)
{
    __shared__ float dt[128 * DT_STRIDE];     // 18 KB staging tile
    __shared__ float pl[16 * PL_STRIDE];      // 33.3 KB p rows

    const int t    = threadIdx.x;
    const int tile = blockIdx.x & 31;
    const int bh   = blockIdx.x >> 5;         // b*H + h
    const int h    = bh & 3;
    const int b    = bh >> 2;
    const int i    = t >> 4;
    const int sub  = t & 15;
    const int iglob = tile * 16 + i;
    const size_t bhN = (size_t)bh * N_;

    // s_i row and a[h] into registers
    float4 s4[8], a4[8];
    {
        const float4* sg = (const float4*)(hsrc + ((bhN + iglob) << 5));
        const float4* ag = (const float4*)(a + h * U_);
#pragma unroll
        for (int q = 0; q < 8; ++q) s4[q] = sg[q];
#pragma unroll
        for (int q = 0; q < 8; ++q) a4[q] = ag[q];
    }
    const float Ai = Arow[bhN + iglob];

    float sc[32];

    // ---------------- Phase A: scores -> registers ----------------
    for (int jt = 0; jt < 4; ++jt) {
        __syncthreads();
        const float4* dg = (const float4*)(hdst + ((bhN + jt * 128) << 5));
#pragma unroll
        for (int q = 0; q < 4; ++q) {
            const int idx = t + 256 * q;
            const int j = idx >> 3, uq = idx & 7;
            *(float4*)&dt[j * DT_STRIDE + uq * 4] = dg[idx];
        }
        __syncthreads();
#pragma unroll
        for (int k = 0; k < 8; ++k) {
            const int jl = sub + 16 * k;
            const float4* dr = (const float4*)&dt[jl * DT_STRIDE];
            float rsum = 0.f;
#pragma unroll
            for (int q = 0; q < 8; ++q) {
                const float4 dv = dr[q];
                const float4 sv = s4[q];
                const float4 av = a4[q];
                float t0;
                t0 = sv.x + dv.x; rsum = fmaf(fmaxf(t0, 0.f), av.x, rsum);
                t0 = sv.y + dv.y; rsum = fmaf(fmaxf(t0, 0.f), av.y, rsum);
                t0 = sv.z + dv.z; rsum = fmaf(fmaxf(t0, 0.f), av.z, rsum);
                t0 = sv.w + dv.w; rsum = fmaf(fmaxf(t0, 0.f), av.w, rsum);
            }
            const float Dj = Drow[bhN + jt * 128 + jl];
            sc[jt * 8 + k] = LEAKY_ALPHA * (Ai + Dj) + (1.f - LEAKY_ALPHA) * rsum;
        }
    }

    // ---------------- Phase B: softmax over the row ----------------
    float m = sc[0];
#pragma unroll
    for (int r = 1; r < 32; ++r) m = fmaxf(m, sc[r]);
    m = fmaxf(m, __shfl_xor(m, 1));
    m = fmaxf(m, __shfl_xor(m, 2));
    m = fmaxf(m, __shfl_xor(m, 4));
    m = fmaxf(m, __shfl_xor(m, 8));

    float sum = 0.f;
#pragma unroll
    for (int jt = 0; jt < 4; ++jt) {
#pragma unroll
        for (int k = 0; k < 8; ++k) {
            const float e = __expf(sc[jt * 8 + k] - m);
            sum += e;
            pl[i * PL_STRIDE + jt * 128 + sub + 16 * k] = e;
        }
    }
    sum += __shfl_xor(sum, 1);
    sum += __shfl_xor(sum, 2);
    sum += __shfl_xor(sum, 4);
    sum += __shfl_xor(sum, 8);
    const float inv = __builtin_amdgcn_rcpf(sum);

    // ---------------- Phase C: out = (p @ h_src) * inv ----------------
    const int u0 = sub * 2;
    float accx = 0.f, accy = 0.f;
    for (int jt = 0; jt < 4; ++jt) {
        __syncthreads();
        const float4* sg = (const float4*)(hsrc + ((bhN + jt * 128) << 5));
#pragma unroll
        for (int q = 0; q < 4; ++q) {
            const int idx = t + 256 * q;
            const int j = idx >> 3, uq = idx & 7;
            *(float4*)&dt[j * DT_STRIDE + uq * 4] = sg[idx];
        }
        __syncthreads();
        const float* prow = &pl[i * PL_STRIDE + jt * 128];
#pragma unroll 4
        for (int jl = 0; jl < 128; jl += 2) {
            const float2 p2 = *(const float2*)&prow[jl];
            const float2 sA = *(const float2*)&dt[jl * DT_STRIDE + u0];
            const float2 sB = *(const float2*)&dt[(jl + 1) * DT_STRIDE + u0];
            accx = fmaf(p2.x, sA.x, accx);
            accy = fmaf(p2.x, sA.y, accy);
            accx = fmaf(p2.y, sB.x, accx);
            accy = fmaf(p2.y, sB.y, accy);
        }
    }
    accx *= inv;
    accy *= inv;
    float2 o; o.x = accx; o.y = accy;
    *(float2*)&out[(size_t)(b * N_ + iglob) * (H_ * U_) + h * U_ + u0] = o;
}

// ---------------------------------------------------------------------------
extern "C" void kernel_launch(void* const* d_in, const int* in_sizes, int n_in,
                              void* d_out, int out_size, void* d_ws, size_t ws_size,
                              hipStream_t stream) {
    const float* x    = (const float*)d_in[0];
    const float* Wsrc = (const float*)d_in[1];
    const float* Wdst = (const float*)d_in[2];
    const float* a    = (const float*)d_in[3];

    float* ws   = (float*)d_ws;
    float* hsrc = ws;
    float* hdst = hsrc + (size_t)B_ * H_ * N_ * U_;
    float* Arow = hdst + (size_t)B_ * H_ * N_ * U_;
    float* Drow = Arow + (size_t)B_ * H_ * N_;

    proj_kernel<<<(B_ * N_) / 16, 256, 0, stream>>>(x, Wsrc, Wdst, a,
                                                    hsrc, hdst, Arow, Drow);
    attn_kernel<<<B_ * H_ * (N_ / 16), 256, 0, stream>>>(hsrc, hdst, Arow, Drow,
                                                         a, (float*)d_out);
}